// Round 8
// baseline (9685.041 us; speedup 1.0000x reference)
//
#include <hip/hip_runtime.h>

typedef unsigned short u16;
typedef unsigned int   u32;
typedef unsigned long long u64;
typedef short s16x4 __attribute__((ext_vector_type(4)));
typedef short s16x8 __attribute__((ext_vector_type(8)));
typedef float f32x4 __attribute__((ext_vector_type(4)));
typedef u32   u32x4 __attribute__((ext_vector_type(4)));

#define GK 1024
#define P64 0x7F7F7F7F7F7F7F7FULL   // bf16 0x7F7F = 3.39e38; |h|<=1 -> never produced

__device__ inline u16 f2bf(float f) {
    u32 u = __builtin_bit_cast(u32, f);
    u += 0x7FFFu + ((u >> 16) & 1u);
    return (u16)(u >> 16);
}
__device__ inline u16 f2h(float f) {
    _Float16 h = (_Float16)f;
    return __builtin_bit_cast(u16, h);
}
__device__ inline float h2f(u16 u) {
    return (float)__builtin_bit_cast(_Float16, u);
}
__device__ inline float fast_sigmoid(float x) {
    return __builtin_amdgcn_rcpf(1.f + __expf(-x));
}
__device__ inline float fast_tanh(float x) {
    return 1.f - 2.f * __builtin_amdgcn_rcpf(1.f + __expf(2.f * x));
}
__device__ inline f32x4 mfma16(s16x8 a, s16x8 b, f32x4 c) {
    return __builtin_amdgcn_mfma_f32_16x16x32_bf16(a, b, c, 0, 0, 0);
}
__device__ inline s16x8 mk8(s16x4 lo, s16x4 hi) {
    return __builtin_shufflevector(lo, hi, 0, 1, 2, 3, 4, 5, 6, 7);
}
__device__ inline u64 aload(const u16* p) {
    return __hip_atomic_load((const u64*)p, __ATOMIC_RELAXED, __HIP_MEMORY_SCOPE_AGENT);
}
// retry until != poison; bounded so a visibility bug fails fast instead of hanging
__device__ inline u64 spin_ok(u64 v, const u16* p) {
    int guard = 0;
    while (v == P64 && ++guard < (1 << 22)) {
        __builtin_amdgcn_s_sleep(1);
        v = aload(p);
    }
    return v;
}

// ---------------- f32 -> bf16 convert (x) ----------------
__global__ void k_f2bf(const float* __restrict__ in, u16* __restrict__ out, int n) {
    int i = (blockIdx.x * 256 + threadIdx.x) * 4;
    if (i < n) {
        float4 v = *(const float4*)(in + i);
        ushort4 o;
        o.x = f2bf(v.x); o.y = f2bf(v.y); o.z = f2bf(v.z); o.w = f2bf(v.w);
        *(ushort4*)(out + i) = o;
    }
}

// ---------------- transpose + convert: out[c][r] = bf16(in[r][c]) ----------------
__global__ void k_transpose_bf(const float* __restrict__ in, u16* __restrict__ out,
                               int R, int C) {
    __shared__ float tile[32][33];
    int tid = threadIdx.x;
    int xs = (tid & 7) * 4;
    int y  = tid >> 3;
    int r0 = blockIdx.y * 32, c0 = blockIdx.x * 32;
    float4 v = *(const float4*)(in + (size_t)(r0 + y) * C + c0 + xs);
    tile[y][xs + 0] = v.x; tile[y][xs + 1] = v.y;
    tile[y][xs + 2] = v.z; tile[y][xs + 3] = v.w;
    __syncthreads();
    ushort4 o;
    o.x = f2bf(tile[xs + 0][y]); o.y = f2bf(tile[xs + 1][y]);
    o.z = f2bf(tile[xs + 2][y]); o.w = f2bf(tile[xs + 3][y]);
    *(ushort4*)(out + (size_t)(c0 + y) * R + r0 + xs) = o;
}

// ---------------- bf16 GEMM: C[m][n] = sum_k A[m][k] * BT[n][k] (+epilogue) ----------------
// MODE 0: A plain [M][1024]; write fp16 gate-interleaved xproj at orow=(m&511)*32+(m>>9).
// MODE 1: A = hseq1 slot base (unit-permuted [t][b][knew]); rows m=(t<<5)|b.
//         B staged with the same k-permutation. orow=(m&31)*512+(m>>5).
//         n<256: softplus(acc+bias)+ymin -> mu; n>=256: acc+b2 -> log_sigma.
template<int MODE>
__launch_bounds__(256, 2)
__global__ void k_gemm(const u16* __restrict__ A, const u16* __restrict__ BT,
                       const float* __restrict__ bias,
                       u16* __restrict__ Cb, float* __restrict__ Cf,
                       const float* __restrict__ b2, const float* __restrict__ ymin,
                       int gridN) {
    int bid = blockIdx.x;
    int m0 = (bid / gridN) * 128, n0 = (bid % gridN) * 128;
    __shared__ u16 As[128 * 40];
    __shared__ u16 Bs[128 * 40];
    int tid = threadIdx.x;
    int lane = tid & 63, w = tid >> 6;
    int wr = w >> 1, wc = w & 1;
    int rr = lane & 15, r16 = lane >> 4;
    f32x4 acc[4][4] = {};
    for (int kt = 0; kt < GK / 32; ++kt) {
        int k0 = kt * 32;
#pragma unroll
        for (int it = 0; it < 2; ++it) {
            int idx = it * 256 + tid;
            int row = idx >> 2, ch = idx & 3;
            if (MODE == 0) {
                *(u32x4*)(&As[row * 40 + ch * 8]) =
                    *(const u32x4*)(A + (size_t)(m0 + row) * GK + k0 + ch * 8);
                *(u32x4*)(&Bs[row * 40 + ch * 8]) =
                    *(const u32x4*)(BT + (size_t)(n0 + row) * GK + k0 + ch * 8);
            } else {
                int m = m0 + row;
                size_t aaddr = (size_t)(m >> 5) * 32768 + (size_t)(m & 31) * 1024
                             + k0 + ch * 8;
                *(u32x4*)(&As[row * 40 + ch * 8]) = *(const u32x4*)(A + aaddr);
                // B staged with k-permutation matching knew layout
                const u16* bp = BT + (size_t)(n0 + row) * GK + k0 + ch * 4;
                *(s16x8*)(&Bs[row * 40 + ch * 8]) =
                    mk8(*(const s16x4*)bp, *(const s16x4*)(bp + 16));
            }
        }
        __syncthreads();
        s16x8 af[4], bfr[4];
#pragma unroll
        for (int i = 0; i < 4; ++i) {
            int abase = (wr * 64 + i * 16 + rr) * 40 + r16 * 4;
            af[i] = mk8(*(const s16x4*)(&As[abase]), *(const s16x4*)(&As[abase + 16]));
            int bbase = (wc * 64 + i * 16 + rr) * 40 + r16 * 4;
            bfr[i] = mk8(*(const s16x4*)(&Bs[bbase]), *(const s16x4*)(&Bs[bbase + 16]));
        }
#pragma unroll
        for (int i = 0; i < 4; ++i)
#pragma unroll
            for (int j = 0; j < 4; ++j)
                acc[i][j] = mfma16(af[i], bfr[j], acc[i][j]);
        __syncthreads();
    }
#pragma unroll
    for (int i = 0; i < 4; ++i) {
#pragma unroll
        for (int j = 0; j < 4; ++j) {
#pragma unroll
            for (int r = 0; r < 4; ++r) {
                int m = m0 + wr * 64 + i * 16 + r16 * 4 + r;
                int n = n0 + wc * 64 + j * 16 + rr;
                float v = acc[i][j][r];
                if (MODE == 0) {
                    v += bias[n];
                    int orow = (m & 511) * 32 + (m >> 9);
                    int colx = ((n & 1023) << 2) | (n >> 10);   // gate-interleaved
                    Cb[(size_t)orow * 4096 + colx] = f2h(v);
                } else {
                    int orow = (m & 31) * 512 + (m >> 5);
                    if (n < 256) {
                        v += bias[n];
                        float sp = fmaxf(v, 0.f) + log1pf(expf(-fabsf(v)));
                        Cf[(size_t)orow * 256 + n] = sp + ymin[n];
                    } else {
                        v += b2[n - 256];
                        Cf[4194304 + (size_t)orow * 256 + (n - 256)] = v;
                    }
                }
            }
        }
    }
}

// ---------------- fused 2-layer persistent LSTM, poison-sync (no barrier) ----------------
// 128 blocks x 512 threads. hseq slot layout: [b(32)][knew(1024)], knew = q*32 + n,
// n = ((k>>2)&3)*8 + (k&3) + ((k>>4)&1)*4 for orig unit q*32+k (matches MFMA A-frag:
// lane r16's contiguous 16B IS its fragment). Block blk owns units
// {g32*32 + sub*4 + i + h*16}, g32=blk>>2, sub=blk&3. Slots pre-poisoned 0x7F7F;
// consumers retry until != poison; producers plain relaxed 8B stores. No flags.
// Waves: grp A (0-3) = (mt,qh): L0 + L1-x for K-half qh, both col-tiles; epilogues.
//        grp B (4-7) = (mt,qh): L1-h for K-half qh -> partial via LDS.
__launch_bounds__(512, 1)
__global__ void k_fused(const u16* __restrict__ Wh0T, const u16* __restrict__ Wx1T,
                        const u16* __restrict__ Wh1T, const u16* __restrict__ xproj,
                        const float* __restrict__ b1,
                        u16* __restrict__ hseq0, u16* __restrict__ hseq1) {
    __shared__ u16 wlds[2][32][2][64][8];    // [layer][q][ct][lane][8] frags, 128 KB
    __shared__ f32x4 part[2][2][4][64];      // [mt][ct][src: A-L0,A-L1x,B0,B1][lane] 16 KB
    int tid = threadIdx.x, blk = blockIdx.x;
    int lane = tid & 63, w = tid >> 6;
    int grp = w >> 2, wl = w & 3;
    int mt = wl >> 1, qh = wl & 1;
    int rr = lane & 15, r16 = lane >> 4;
    int g32 = blk >> 2, sub = blk & 3;

    // ---- preload Wh0/Wh1 fragments into LDS (each wave: its layer, 8 q's) ----
    {
        const u16* WT = (grp == 0) ? Wh0T : Wh1T;
#pragma unroll
        for (int qq = 0; qq < 8; ++qq) {
            int q = wl * 8 + qq;
#pragma unroll
            for (int ct = 0; ct < 2; ++ct) {
                int unit = g32 * 32 + sub * 4 + (rr >> 2) + ct * 16;
                const u16* src = WT + (size_t)((rr & 3) * 1024 + unit) * GK + q * 32 + r16 * 4;
                *(s16x8*)(&wlds[grp][q][ct][lane][0]) =
                    mk8(*(const s16x4*)src, *(const s16x4*)(src + 16));
            }
        }
    }

    // epilogue lane identity (grp A, col-tile ct=qh)
    int b_ = mt * 16 + (lane >> 4) * 4 + (lane & 3);
    int unitE = g32 * 32 + sub * 4 + ((lane >> 2) & 3) + qh * 16;
    float c0 = 0.f, c1 = 0.f;
    float b1r[4];
#pragma unroll
    for (int g = 0; g < 4; ++g) b1r[g] = b1[g * 1024 + unitE];
    const u16* xp = xproj + (size_t)b_ * 4096 + (size_t)unitE * 4;
    const int soff = b_ * 1024 + g32 * 32 + sub * 8 + qh * 4;       // 8B store slot
    const int cbase = (mt * 16 + rr) * 1024 + qh * 512 + r16 * 8;   // load base

    // Wx1 stream base (ct=0 col; ct=1 at +16*GK), anti-LICM'd per round
    u64 wpx_u = (u64)(uintptr_t)(Wx1T +
        (size_t)((rr & 3) * 1024 + g32 * 32 + sub * 4 + (rr >> 2)) * GK + r16 * 4);

    __syncthreads();   // wlds ready

    for (int r = 0; r <= 512; ++r) {
        f32x4 a0[2] = {}, a1[2] = {};   // A: L0 / L1x per col-tile; B: L1h in a0
        u64 xv = 0;
        if (grp == 0) {
            if (r < 512) xv = *(const u64*)(xp + (size_t)r * 131072);
            asm volatile("" : "+v"(wpx_u));
            const u16* wpx = (const u16*)(uintptr_t)wpx_u;
            const u16* hp = hseq0 + (size_t)r * 32768 + cbase;
            u64 lo[16], hi[16];
#pragma unroll
            for (int j = 0; j < 16; ++j) {
                lo[j] = aload(hp + j * 32);
                hi[j] = aload(hp + j * 32 + 4);
            }
#pragma unroll
            for (int j = 0; j < 16; ++j) {
                lo[j] = spin_ok(lo[j], hp + j * 32);
                hi[j] = spin_ok(hi[j], hp + j * 32 + 4);
                s16x8 a = mk8(__builtin_bit_cast(s16x4, lo[j]),
                              __builtin_bit_cast(s16x4, hi[j]));
                int q = qh * 16 + j;
                s16x8 bw0 = *(const s16x8*)(&wlds[0][q][0][lane][0]);
                s16x8 bw1 = *(const s16x8*)(&wlds[0][q][1][lane][0]);
                const u16* bp = wpx + q * 32;
                s16x8 bx0 = mk8(*(const s16x4*)bp, *(const s16x4*)(bp + 16));
                s16x8 bx1 = mk8(*(const s16x4*)(bp + 16384),
                                *(const s16x4*)(bp + 16384 + 16));
                a0[0] = mfma16(a, bw0, a0[0]);
                a0[1] = mfma16(a, bw1, a0[1]);
                a1[0] = mfma16(a, bx0, a1[0]);
                a1[1] = mfma16(a, bx1, a1[1]);
            }
            part[mt][1 - qh][0][lane] = a0[1 - qh];
            part[mt][1 - qh][1][lane] = a1[1 - qh];
        } else {
            if (r > 0) {
                const u16* hp = hseq1 + (size_t)(r - 1) * 32768 + cbase;
                u64 lo[16], hi[16];
#pragma unroll
                for (int j = 0; j < 16; ++j) {
                    lo[j] = aload(hp + j * 32);
                    hi[j] = aload(hp + j * 32 + 4);
                }
#pragma unroll
                for (int j = 0; j < 16; ++j) {
                    lo[j] = spin_ok(lo[j], hp + j * 32);
                    hi[j] = spin_ok(hi[j], hp + j * 32 + 4);
                    s16x8 a = mk8(__builtin_bit_cast(s16x4, lo[j]),
                                  __builtin_bit_cast(s16x4, hi[j]));
                    int q = qh * 16 + j;
                    s16x8 bw0 = *(const s16x8*)(&wlds[1][q][0][lane][0]);
                    s16x8 bw1 = *(const s16x8*)(&wlds[1][q][1][lane][0]);
                    a0[0] = mfma16(a, bw0, a0[0]);
                    a0[1] = mfma16(a, bw1, a0[1]);
                }
            }
            part[mt][0][2 + qh][lane] = a0[0];
            part[mt][1][2 + qh][lane] = a0[1];
        }
        __syncthreads();   // partials published

        if (grp == 0) {
            // ---- L0 epilogue (col-tile qh) ----
            if (r < 512) {
                f32x4 acc = a0[qh] + part[mt][qh][0][lane];
                float r0 = acc[0], r1 = acc[1], r2 = acc[2], r3 = acc[3];
                float x0 = __shfl_xor(r0, 1), x1 = __shfl_xor(r1, 1);
                float x2 = __shfl_xor(r2, 1), x3 = __shfl_xor(r3, 1);
                bool o1 = lane & 1;
                float s0 = o1 ? x1 : r0, s1 = o1 ? r1 : x0;
                float s2 = o1 ? x3 : r2, s3 = o1 ? r3 : x2;
                float y0 = __shfl_xor(s0, 2), y1 = __shfl_xor(s1, 2);
                float y2 = __shfl_xor(s2, 2), y3 = __shfl_xor(s3, 2);
                bool o2 = lane & 2;
                float gi = (o2 ? y2 : s0) + h2f((u16)(xv));
                float gf = (o2 ? y3 : s1) + h2f((u16)(xv >> 16));
                float gg = (o2 ? s2 : y0) + h2f((u16)(xv >> 32));
                float go = (o2 ? s3 : y1) + h2f((u16)(xv >> 48));
                float I  = fast_sigmoid(gi);
                float Fg = fast_sigmoid(gf);
                float G  = fast_tanh(gg);
                float O  = fast_sigmoid(go);
                c0 = Fg * c0 + I * G;
                u32 hq = (u32)f2bf(O * fast_tanh(c0));
                u32 o4 = (u32)__shfl_xor((int)hq, 4);
                u32 m32 = (lane & 4) ? ((o4 & 0xffffu) | (hq << 16))
                                     : ((hq & 0xffffu) | (o4 << 16));
                u32 o8 = (u32)__shfl_xor((int)m32, 8);
                u64 m64 = (lane & 8) ? (((u64)o8) | ((u64)m32 << 32))
                                     : (((u64)m32) | ((u64)o8 << 32));
                if ((lane & 12) == 0)
                    __hip_atomic_store((u64*)(hseq0 + (size_t)(r + 1) * 32768 + soff),
                                       m64, __ATOMIC_RELAXED, __HIP_MEMORY_SCOPE_AGENT);
            }
            // ---- L1 epilogue (x-part + partner-x + B partials) ----
            if (r > 0) {
                f32x4 acc = a1[qh] + part[mt][qh][1][lane]
                          + part[mt][qh][2][lane] + part[mt][qh][3][lane];
                float r0 = acc[0], r1 = acc[1], r2 = acc[2], r3 = acc[3];
                float x0 = __shfl_xor(r0, 1), x1 = __shfl_xor(r1, 1);
                float x2 = __shfl_xor(r2, 1), x3 = __shfl_xor(r3, 1);
                bool o1 = lane & 1;
                float s0 = o1 ? x1 : r0, s1 = o1 ? r1 : x0;
                float s2 = o1 ? x3 : r2, s3 = o1 ? r3 : x2;
                float y0 = __shfl_xor(s0, 2), y1 = __shfl_xor(s1, 2);
                float y2 = __shfl_xor(s2, 2), y3 = __shfl_xor(s3, 2);
                bool o2 = lane & 2;
                float gi = (o2 ? y2 : s0) + b1r[0];
                float gf = (o2 ? y3 : s1) + b1r[1];
                float gg = (o2 ? s2 : y0) + b1r[2];
                float go = (o2 ? s3 : y1) + b1r[3];
                float I  = fast_sigmoid(gi);
                float Fg = fast_sigmoid(gf);
                float G  = fast_tanh(gg);
                float O  = fast_sigmoid(go);
                c1 = Fg * c1 + I * G;
                u32 hq = (u32)f2bf(O * fast_tanh(c1));
                u32 o4 = (u32)__shfl_xor((int)hq, 4);
                u32 m32 = (lane & 4) ? ((o4 & 0xffffu) | (hq << 16))
                                     : ((hq & 0xffffu) | (o4 << 16));
                u32 o8 = (u32)__shfl_xor((int)m32, 8);
                u64 m64 = (lane & 8) ? (((u64)o8) | ((u64)m32 << 32))
                                     : (((u64)m32) | ((u64)o8 << 32));
                if ((lane & 12) == 0)
                    __hip_atomic_store((u64*)(hseq1 + (size_t)r * 32768 + soff),
                                       m64, __ATOMIC_RELAXED, __HIP_MEMORY_SCOPE_AGENT);
            }
        }
        __syncthreads();   // protects part[] reuse next round
    }
}

extern "C" void kernel_launch(void* const* d_in, const int* in_sizes, int n_in,
                              void* d_out, int out_size, void* d_ws, size_t ws_size,
                              hipStream_t stream) {
    const float* x   = (const float*)d_in[0];
    const float* Wx  = (const float*)d_in[1];
    const float* Wh  = (const float*)d_in[2];
    const float* b   = (const float*)d_in[3];
    const float* Wmu = (const float*)d_in[4];
    const float* bmu = (const float*)d_in[5];
    const float* Wls = (const float*)d_in[6];
    const float* bls = (const float*)d_in[7];
    const float* ym  = (const float*)d_in[8];
    float* out = (float*)d_out;

    // workspace (236,060,672 B):
    // [0)            hseq0 [513][32768] u16 = 33,619,968  (aliases xbf 32 MiB)
    // [33,619,968)   hseq1 33,619,968
    // [67,239,936)   wxT   16,777,216   [2][4096][1024]
    // [84,017,152)   whT   16,777,216
    // [100,794,368)  whdT   1,048,576   [512][1024]
    // [101,842,944)  xproj 134,217,728  fp16 gate-interleaved [t*32+b][4096]
    char* ws = (char*)d_ws;
    u16* hseq0 = (u16*)(ws);
    u16* xbf   = (u16*)(ws);
    u16* hseq1 = (u16*)(ws + 33619968);
    u16* wxT   = (u16*)(ws + 67239936);
    u16* whT   = (u16*)(ws + 84017152);
    u16* whdT  = (u16*)(ws + 100794368);
    u16* xproj = (u16*)(ws + 101842944);

    // hseq1: slot0 = zeros (h1 init), rest = poison
    hipMemsetAsync(hseq1, 0, 65536, stream);
    hipMemsetAsync(hseq1 + 32768, 0x7F, 33619968 - 65536, stream);

    // prep
    k_f2bf<<<16384, 256, 0, stream>>>(x, xbf, 16777216);
    dim3 tg(128, 32);
    k_transpose_bf<<<tg, 256, 0, stream>>>(Wx,           wxT,           1024, 4096);
    k_transpose_bf<<<tg, 256, 0, stream>>>(Wx + 4194304, wxT + 4194304, 1024, 4096);
    k_transpose_bf<<<tg, 256, 0, stream>>>(Wh,           whT,           1024, 4096);
    k_transpose_bf<<<tg, 256, 0, stream>>>(Wh + 4194304, whT + 4194304, 1024, 4096);
    dim3 hg(8, 32);
    k_transpose_bf<<<hg, 256, 0, stream>>>(Wmu, whdT,          1024, 256);
    k_transpose_bf<<<hg, 256, 0, stream>>>(Wls, whdT + 262144, 1024, 256);

    // layer-0 x-projection (reads xbf, writes xproj)
    k_gemm<0><<<4096, 256, 0, stream>>>(xbf, wxT, b, xproj, nullptr, nullptr, nullptr, 32);

    // hseq0 (xbf now dead): slot0 = zeros, rest = poison
    hipMemsetAsync(hseq0, 0, 65536, stream);
    hipMemsetAsync(hseq0 + 32768, 0x7F, 33619968 - 65536, stream);

    // fused 2-layer recurrence, barrier-free
    k_fused<<<128, 512, 0, stream>>>(whT, wxT + 4194304, whT + 4194304, xproj,
                                     b + 4096, hseq0, hseq1);

    // heads (mu || log_sigma) from hseq1 slots 1..512 (k-permuted A and B)
    k_gemm<1><<<512, 256, 0, stream>>>(hseq1 + 32768, whdT, bmu, nullptr, out,
                                       bls, ym, 4);
}

// Round 11
// 8215.808 us; speedup vs baseline: 1.1788x; 1.1788x over previous
//
#include <hip/hip_runtime.h>

typedef unsigned short u16;
typedef unsigned int   u32;
typedef unsigned long long u64;
typedef short s16x4 __attribute__((ext_vector_type(4)));
typedef short s16x8 __attribute__((ext_vector_type(8)));
typedef float f32x4 __attribute__((ext_vector_type(4)));
typedef u32   u32x4 __attribute__((ext_vector_type(4)));

#define GK 1024

__device__ inline u16 f2bf(float f) {
    u32 u = __builtin_bit_cast(u32, f);
    u += 0x7FFFu + ((u >> 16) & 1u);
    return (u16)(u >> 16);
}
__device__ inline u16 f2h(float f) {
    _Float16 h = (_Float16)f;
    return __builtin_bit_cast(u16, h);
}
__device__ inline float h2f(u16 u) {
    return (float)__builtin_bit_cast(_Float16, u);
}
__device__ inline float fast_sigmoid(float x) {
    return __builtin_amdgcn_rcpf(1.f + __expf(-x));
}
__device__ inline float fast_tanh(float x) {
    return 1.f - 2.f * __builtin_amdgcn_rcpf(1.f + __expf(2.f * x));
}
__device__ inline f32x4 mfma16(s16x8 a, s16x8 b, f32x4 c) {
    return __builtin_amdgcn_mfma_f32_16x16x32_bf16(a, b, c, 0, 0, 0);
}
__device__ inline s16x8 mk8(s16x4 lo, s16x4 hi) {
    return __builtin_shufflevector(lo, hi, 0, 1, 2, 3, 4, 5, 6, 7);
}
__device__ inline u64 ald(const u16* p) {   // agent-scope (sc1) 8B load
    return __hip_atomic_load((const u64*)p, __ATOMIC_RELAXED, __HIP_MEMORY_SCOPE_AGENT);
}

// ---------------- f32 -> bf16 convert (x) ----------------
__global__ void k_f2bf(const float* __restrict__ in, u16* __restrict__ out, int n) {
    int i = (blockIdx.x * 256 + threadIdx.x) * 4;
    if (i < n) {
        float4 v = *(const float4*)(in + i);
        ushort4 o;
        o.x = f2bf(v.x); o.y = f2bf(v.y); o.z = f2bf(v.z); o.w = f2bf(v.w);
        *(ushort4*)(out + i) = o;
    }
}

// ---------------- transpose + convert: out[c][r] = bf16(in[r][c]) ----------------
__global__ void k_transpose_bf(const float* __restrict__ in, u16* __restrict__ out,
                               int R, int C) {
    __shared__ float tile[32][33];
    int tid = threadIdx.x;
    int xs = (tid & 7) * 4;
    int y  = tid >> 3;
    int r0 = blockIdx.y * 32, c0 = blockIdx.x * 32;
    float4 v = *(const float4*)(in + (size_t)(r0 + y) * C + c0 + xs);
    tile[y][xs + 0] = v.x; tile[y][xs + 1] = v.y;
    tile[y][xs + 2] = v.z; tile[y][xs + 3] = v.w;
    __syncthreads();
    ushort4 o;
    o.x = f2bf(tile[xs + 0][y]); o.y = f2bf(tile[xs + 1][y]);
    o.z = f2bf(tile[xs + 2][y]); o.w = f2bf(tile[xs + 3][y]);
    *(ushort4*)(out + (size_t)(c0 + y) * R + r0 + xs) = o;
}

// ---------------- unpack permuted hseq1 -> plain [t*32+b][1024] ----------------
// in slot s=t+1 layout [q][b][ri*8+j]; orig k = q*32 + ri*4 + (j&3) + 16*(j>>2)
__global__ void k_unpack(const u16* __restrict__ in, u16* __restrict__ out) {
    int idx = blockIdx.x * 256 + threadIdx.x;   // 512*4096 chunks
    int slot = idx >> 12;
    int c = idx & 4095;
    int q = c >> 7, b = (c >> 2) & 31, ri = c & 3;
    const u16* p = in + (size_t)(slot + 1) * 32768 + q * 1024 + b * 32 + ri * 8;
    u64 lo = *(const u64*)p;
    u64 hi = *(const u64*)(p + 4);
    u16* o = out + (size_t)(slot * 32 + b) * 1024 + q * 32 + ri * 4;
    *(u64*)o = lo;
    *(u64*)(o + 16) = hi;
}

// ---------------- bf16 GEMM: C[m][n] = sum_k A[m][k] * BT[n][k] (+epilogue) ----------------
// A plain [M][1024] both modes.
// MODE 0: xproj: orow=(m&511)*32+(m>>9), fp16 gate-interleaved.
// MODE 1: heads: orow=(m&31)*512+(m>>5); n<256 softplus+ymin -> mu; n>=256 -> log_sigma.
template<int MODE>
__launch_bounds__(256, 2)
__global__ void k_gemm(const u16* __restrict__ A, const u16* __restrict__ BT,
                       const float* __restrict__ bias,
                       u16* __restrict__ Cb, float* __restrict__ Cf,
                       const float* __restrict__ b2, const float* __restrict__ ymin,
                       int gridN) {
    int bid = blockIdx.x;
    int m0 = (bid / gridN) * 128, n0 = (bid % gridN) * 128;
    __shared__ u16 As[128 * 40];
    __shared__ u16 Bs[128 * 40];
    int tid = threadIdx.x;
    int lane = tid & 63, w = tid >> 6;
    int wr = w >> 1, wc = w & 1;
    int rr = lane & 15, r16 = lane >> 4;
    f32x4 acc[4][4] = {};
    for (int kt = 0; kt < GK / 32; ++kt) {
        int k0 = kt * 32;
#pragma unroll
        for (int it = 0; it < 2; ++it) {
            int idx = it * 256 + tid;
            int row = idx >> 2, ch = idx & 3;
            *(u32x4*)(&As[row * 40 + ch * 8]) =
                *(const u32x4*)(A + (size_t)(m0 + row) * GK + k0 + ch * 8);
            *(u32x4*)(&Bs[row * 40 + ch * 8]) =
                *(const u32x4*)(BT + (size_t)(n0 + row) * GK + k0 + ch * 8);
        }
        __syncthreads();
        s16x8 af[4], bfr[4];
#pragma unroll
        for (int i = 0; i < 4; ++i) {
            int abase = (wr * 64 + i * 16 + rr) * 40 + r16 * 4;
            af[i] = mk8(*(const s16x4*)(&As[abase]), *(const s16x4*)(&As[abase + 16]));
            int bbase = (wc * 64 + i * 16 + rr) * 40 + r16 * 4;
            bfr[i] = mk8(*(const s16x4*)(&Bs[bbase]), *(const s16x4*)(&Bs[bbase + 16]));
        }
#pragma unroll
        for (int i = 0; i < 4; ++i)
#pragma unroll
            for (int j = 0; j < 4; ++j)
                acc[i][j] = mfma16(af[i], bfr[j], acc[i][j]);
        __syncthreads();
    }
#pragma unroll
    for (int i = 0; i < 4; ++i) {
#pragma unroll
        for (int j = 0; j < 4; ++j) {
#pragma unroll
            for (int r = 0; r < 4; ++r) {
                int m = m0 + wr * 64 + i * 16 + r16 * 4 + r;
                int n = n0 + wc * 64 + j * 16 + rr;
                float v = acc[i][j][r];
                if (MODE == 0) {
                    v += bias[n];
                    int orow = (m & 511) * 32 + (m >> 9);
                    int colx = ((n & 1023) << 2) | (n >> 10);   // gate-interleaved
                    Cb[(size_t)orow * 4096 + colx] = f2h(v);
                } else {
                    int orow = (m & 31) * 512 + (m >> 5);
                    if (n < 256) {
                        v += bias[n];
                        float sp = fmaxf(v, 0.f) + log1pf(expf(-fabsf(v)));
                        Cf[(size_t)orow * 256 + n] = sp + ymin[n];
                    } else {
                        v += b2[n - 256];
                        Cf[4194304 + (size_t)orow * 256 + (n - 256)] = v;
                    }
                }
            }
        }
    }
}

// ---------------- fused 2-layer persistent LSTM (r6 skeleton + coalesced h) ----------------
// 128 blocks x 512 threads. h slot layout: [q(32)][b(32)][32] with fragment permutation
// (elem ri*8+j <-> orig k = ri*4+(j&3)+16*(j>>2)): a wave's per-q load is contiguous 1KB.
// Waves (grp, mt, qh): grp A = L0 + L1-x (Wx1 streamed), K-half qh, partials for both
// col-groups nt; grp B = L1-h K-half qh. Partials combined via LDS (r8 pattern).
// All h loads/stores sc1 (agent); flag sync = r6 verbatim.
__launch_bounds__(512, 1)
__global__ void k_fused(const u16* __restrict__ Wh0T, const u16* __restrict__ Wx1T,
                        const u16* __restrict__ Wh1T, const u16* __restrict__ xproj,
                        const float* __restrict__ b1,
                        u16* __restrict__ hseq0, u16* __restrict__ hseq1,
                        u32* __restrict__ flags) {
    __shared__ u16 wlds[2][32][2][64][8];    // [layer][q][nt][lane][8], 128 KB
    __shared__ f32x4 part[2][2][4][64];      // [mt][nt][src: A-L0, A-L1x, B-qh0, B-qh1]
    int tid = threadIdx.x, blk = blockIdx.x;
    int lane = tid & 63, w = tid >> 6;
    int grp = w >> 2, wl = w & 3;
    int mt = wl >> 1, qh = wl & 1;
    int u0 = blk * 8;
    int rr = lane & 15, r16 = lane >> 4;

    // ---- preload Wh frags into LDS: waves {0,1} -> layer0, {4,5} -> layer1 ----
    if (wl < 2) {
        int ntp = wl;
        int cg = (rr & 3) * 1024 + u0 + ntp * 4 + (rr >> 2);
        const u16* wsrc = (grp == 0 ? Wh0T : Wh1T) + (size_t)cg * GK + r16 * 4;
#pragma unroll
        for (int q = 0; q < 32; ++q) {
            *(s16x8*)(&wlds[grp][q][ntp][lane][0]) =
                mk8(*(const s16x4*)(wsrc + q * 32), *(const s16x4*)(wsrc + q * 32 + 16));
        }
    }
    // Wx1 stream base (grp A): nt=0 col group; nt=1 at +4*GK elements
    u64 wpx_u = (u64)(uintptr_t)(Wx1T +
        (size_t)((rr & 3) * 1024 + u0 + (rr >> 2)) * GK + r16 * 4);

    // epilogue identity: thread -> (batch b_, unit u0 + qh*4 + uu)
    int b_ = mt * 16 + (lane >> 4) * 4 + (lane & 3);
    int uu = (lane >> 2) & 3;
    int unit = u0 + qh * 4 + uu;
    float c0 = 0.f, c1 = 0.f;
    float b1r[4];
#pragma unroll
    for (int g = 0; g < 4; ++g) b1r[g] = b1[g * 1024 + unit];
    const u16* xp = xproj + (size_t)b_ * 4096 + (size_t)unit * 4;

    // producer store slot (elements): q = blk>>2; s = blk&3; co = ((s&1)*2+qh)*8 + (s>>1)*4
    int sblk = blk & 3;
    const int soff = (blk >> 2) * 1024 + b_ * 32 + (((sblk & 1) * 2 + qh) * 8 + (sblk >> 1) * 4);
    // consumer base (elements): q-half qh, rows mt*16.., lane chunk
    const int cbase = qh * 16384 + mt * 512 + rr * 32 + r16 * 8;

    __syncthreads();   // wlds ready

    for (int r = 0; r <= 512; ++r) {
        // ---- wave 0 polls all 128 flags >= r (sc1); barrier releases block ----
        if (w == 0) {
            u32 tgt = (u32)r;
            while (true) {
                u32 v0 = __hip_atomic_load(&flags[lane], __ATOMIC_RELAXED,
                                           __HIP_MEMORY_SCOPE_AGENT);
                u32 v1 = __hip_atomic_load(&flags[64 + lane], __ATOMIC_RELAXED,
                                           __HIP_MEMORY_SCOPE_AGENT);
                if (__all((v0 >= tgt) & (v1 >= tgt))) break;
                __builtin_amdgcn_s_sleep(1);
            }
        }
        __syncthreads();
        __builtin_amdgcn_sched_barrier(0);

        f32x4 a0[2] = {}, a1[2] = {};
        u64 xv = 0;
        if (grp == 0) {
            if (r < 512) xv = *(const u64*)(xp + (size_t)r * 131072);
            asm volatile("" : "+v"(wpx_u));   // defeat LICM of Wx1 stream loads
            const u16* wpx = (const u16*)(uintptr_t)wpx_u;
            const u16* hp = hseq0 + (size_t)r * 32768 + cbase;
#pragma unroll
            for (int c = 0; c < 4; ++c) {
                u64 lo4[4], hi4[4];
                s16x8 bx0[4], bx1[4];
#pragma unroll
                for (int j = 0; j < 4; ++j) {
                    int jj = c * 4 + j;
                    int q = qh * 16 + jj;
                    lo4[j] = ald(hp + jj * 1024);
                    hi4[j] = ald(hp + jj * 1024 + 4);
                    const u16* bp = wpx + q * 32;
                    bx0[j] = mk8(*(const s16x4*)bp, *(const s16x4*)(bp + 16));
                    bx1[j] = mk8(*(const s16x4*)(bp + 4096),
                                 *(const s16x4*)(bp + 4096 + 16));
                }
#pragma unroll
                for (int j = 0; j < 4; ++j) {
                    int q = qh * 16 + c * 4 + j;
                    s16x8 a = mk8(__builtin_bit_cast(s16x4, lo4[j]),
                                  __builtin_bit_cast(s16x4, hi4[j]));
                    a0[0] = mfma16(a, *(const s16x8*)(&wlds[0][q][0][lane][0]), a0[0]);
                    a0[1] = mfma16(a, *(const s16x8*)(&wlds[0][q][1][lane][0]), a0[1]);
                    a1[0] = mfma16(a, bx0[j], a1[0]);
                    a1[1] = mfma16(a, bx1[j], a1[1]);
                }
            }
            part[mt][1 - qh][0][lane] = a0[1 - qh];
            part[mt][1 - qh][1][lane] = a1[1 - qh];
        } else {
            if (r > 0) {
                const u16* hp = hseq1 + (size_t)(r - 1) * 32768 + cbase;
#pragma unroll
                for (int c = 0; c < 4; ++c) {
                    u64 lo4[4], hi4[4];
#pragma unroll
                    for (int j = 0; j < 4; ++j) {
                        int jj = c * 4 + j;
                        lo4[j] = ald(hp + jj * 1024);
                        hi4[j] = ald(hp + jj * 1024 + 4);
                    }
#pragma unroll
                    for (int j = 0; j < 4; ++j) {
                        int q = qh * 16 + c * 4 + j;
                        s16x8 a = mk8(__builtin_bit_cast(s16x4, lo4[j]),
                                      __builtin_bit_cast(s16x4, hi4[j]));
                        a0[0] = mfma16(a, *(const s16x8*)(&wlds[1][q][0][lane][0]), a0[0]);
                        a0[1] = mfma16(a, *(const s16x8*)(&wlds[1][q][1][lane][0]), a0[1]);
                    }
                }
            }
            part[mt][0][2 + qh][lane] = a0[0];
            part[mt][1][2 + qh][lane] = a0[1];
        }
        __syncthreads();   // partials published

        if (grp == 0) {
            // ---- L0 epilogue (col-group nt=qh) ----
            if (r < 512) {
                f32x4 acc = a0[qh] + part[mt][qh][0][lane];
                float r0 = acc[0], r1 = acc[1], r2 = acc[2], r3 = acc[3];
                float x0 = __shfl_xor(r0, 1), x1 = __shfl_xor(r1, 1);
                float x2 = __shfl_xor(r2, 1), x3 = __shfl_xor(r3, 1);
                bool o1 = lane & 1;
                float s0 = o1 ? x1 : r0, s1 = o1 ? r1 : x0;
                float s2 = o1 ? x3 : r2, s3 = o1 ? r3 : x2;
                float y0 = __shfl_xor(s0, 2), y1 = __shfl_xor(s1, 2);
                float y2 = __shfl_xor(s2, 2), y3 = __shfl_xor(s3, 2);
                bool o2 = lane & 2;
                float gi = (o2 ? y2 : s0) + h2f((u16)(xv));
                float gf = (o2 ? y3 : s1) + h2f((u16)(xv >> 16));
                float gg = (o2 ? s2 : y0) + h2f((u16)(xv >> 32));
                float go = (o2 ? s3 : y1) + h2f((u16)(xv >> 48));
                float I  = fast_sigmoid(gi);
                float Fg = fast_sigmoid(gf);
                float G  = fast_tanh(gg);
                float O  = fast_sigmoid(go);
                c0 = Fg * c0 + I * G;
                u32 hq = (u32)f2bf(O * fast_tanh(c0));
                u32 o4 = (u32)__shfl_xor((int)hq, 4);
                u32 m32 = (lane & 4) ? ((o4 & 0xffffu) | (hq << 16))
                                     : ((hq & 0xffffu) | (o4 << 16));
                u32 o8 = (u32)__shfl_xor((int)m32, 8);
                u64 m64 = (lane & 8) ? (((u64)o8) | ((u64)m32 << 32))
                                     : (((u64)m32) | ((u64)o8 << 32));
                if ((lane & 12) == 0)
                    __hip_atomic_store((u64*)(hseq0 + (size_t)(r + 1) * 32768 + soff),
                                       m64, __ATOMIC_RELAXED, __HIP_MEMORY_SCOPE_AGENT);
            }
            // ---- L1 epilogue: own L1x + partner L1x + B's two L1h partials ----
            if (r > 0) {
                f32x4 acc = a1[qh] + part[mt][qh][1][lane]
                          + part[mt][qh][2][lane] + part[mt][qh][3][lane];
                float r0 = acc[0], r1 = acc[1], r2 = acc[2], r3 = acc[3];
                float x0 = __shfl_xor(r0, 1), x1 = __shfl_xor(r1, 1);
                float x2 = __shfl_xor(r2, 1), x3 = __shfl_xor(r3, 1);
                bool o1 = lane & 1;
                float s0 = o1 ? x1 : r0, s1 = o1 ? r1 : x0;
                float s2 = o1 ? x3 : r2, s3 = o1 ? r3 : x2;
                float y0 = __shfl_xor(s0, 2), y1 = __shfl_xor(s1, 2);
                float y2 = __shfl_xor(s2, 2), y3 = __shfl_xor(s3, 2);
                bool o2 = lane & 2;
                float gi = (o2 ? y2 : s0) + b1r[0];
                float gf = (o2 ? y3 : s1) + b1r[1];
                float gg = (o2 ? s2 : y0) + b1r[2];
                float go = (o2 ? s3 : y1) + b1r[3];
                float I  = fast_sigmoid(gi);
                float Fg = fast_sigmoid(gf);
                float G  = fast_tanh(gg);
                float O  = fast_sigmoid(go);
                c1 = Fg * c1 + I * G;
                u32 hq = (u32)f2bf(O * fast_tanh(c1));
                u32 o4 = (u32)__shfl_xor((int)hq, 4);
                u32 m32 = (lane & 4) ? ((o4 & 0xffffu) | (hq << 16))
                                     : ((hq & 0xffffu) | (o4 << 16));
                u32 o8 = (u32)__shfl_xor((int)m32, 8);
                u64 m64 = (lane & 8) ? (((u64)o8) | ((u64)m32 << 32))
                                     : (((u64)m32) | ((u64)o8 << 32));
                if ((lane & 12) == 0)
                    __hip_atomic_store((u64*)(hseq1 + (size_t)r * 32768 + soff),
                                       m64, __ATOMIC_RELAXED, __HIP_MEMORY_SCOPE_AGENT);
            }
        }
        __syncthreads();   // drains sc1 stores (vmcnt) before flag post
        if (tid == 0)
            __hip_atomic_store(&flags[blk], (u32)(r + 1), __ATOMIC_RELAXED,
                               __HIP_MEMORY_SCOPE_AGENT);
    }
}

extern "C" void kernel_launch(void* const* d_in, const int* in_sizes, int n_in,
                              void* d_out, int out_size, void* d_ws, size_t ws_size,
                              hipStream_t stream) {
    const float* x   = (const float*)d_in[0];
    const float* Wx  = (const float*)d_in[1];
    const float* Wh  = (const float*)d_in[2];
    const float* b   = (const float*)d_in[3];
    const float* Wmu = (const float*)d_in[4];
    const float* bmu = (const float*)d_in[5];
    const float* Wls = (const float*)d_in[6];
    const float* bls = (const float*)d_in[7];
    const float* ym  = (const float*)d_in[8];
    float* out = (float*)d_out;

    // workspace (236,061,184 B):
    // [0)            hseq0 [513][32768] u16 = 33,619,968  (aliases xbf 32 MiB; sc1-read only)
    // [33,619,968)   hseq1 33,619,968
    // [67,239,936)   wxT   16,777,216   [2][4096][1024]
    // [84,017,152)   whT   16,777,216
    // [100,794,368)  whdT   1,048,576   [512][1024]
    // [101,842,944)  xproj 134,217,728  (reused as h1lin 32MB after k_fused)
    // [236,060,672)  flags 512
    char* ws = (char*)d_ws;
    u16* hseq0 = (u16*)(ws);
    u16* xbf   = (u16*)(ws);
    u16* hseq1 = (u16*)(ws + 33619968);
    u16* wxT   = (u16*)(ws + 67239936);
    u16* whT   = (u16*)(ws + 84017152);
    u16* whdT  = (u16*)(ws + 100794368);
    u16* xproj = (u16*)(ws + 101842944);
    u16* h1lin = xproj;   // xproj dead after k_fused
    u32* flags = (u32*)(ws + 236060672);

    // prep
    k_f2bf<<<16384, 256, 0, stream>>>(x, xbf, 16777216);
    dim3 tg(128, 32);
    k_transpose_bf<<<tg, 256, 0, stream>>>(Wx,           wxT,           1024, 4096);
    k_transpose_bf<<<tg, 256, 0, stream>>>(Wx + 4194304, wxT + 4194304, 1024, 4096);
    k_transpose_bf<<<tg, 256, 0, stream>>>(Wh,           whT,           1024, 4096);
    k_transpose_bf<<<tg, 256, 0, stream>>>(Wh + 4194304, whT + 4194304, 1024, 4096);
    dim3 hg(8, 32);
    k_transpose_bf<<<hg, 256, 0, stream>>>(Wmu, whdT,          1024, 256);
    k_transpose_bf<<<hg, 256, 0, stream>>>(Wls, whdT + 262144, 1024, 256);

    // layer-0 x-projection (reads xbf, writes xproj)
    k_gemm<0><<<4096, 256, 0, stream>>>(xbf, wxT, b, xproj, nullptr, nullptr, nullptr, 32);

    // zero initial h slots + flags (xbf dead now; hseq0 aliases it)
    hipMemsetAsync(hseq0, 0, 65536, stream);
    hipMemsetAsync(hseq1, 0, 65536, stream);
    hipMemsetAsync(flags, 0, 512, stream);

    // fused 2-layer recurrence (coalesced sc1 h traffic)
    k_fused<<<128, 512, 0, stream>>>(whT, wxT + 4194304, whT + 4194304, xproj,
                                     b + 4096, hseq0, hseq1, flags);

    // unpack hseq1 (permuted) -> h1lin (plain rows t*32+b), then heads
    k_unpack<<<8192, 256, 0, stream>>>(hseq1, h1lin);
    k_gemm<1><<<512, 256, 0, stream>>>(h1lin, whdT, bmu, nullptr, out, bls, ym, 4);
}